// Round 10
// baseline (4318.563 us; speedup 1.0000x reference)
//
#include <hip/hip_runtime.h>
#include <hip/hip_bf16.h>

typedef __hip_bfloat16 bf16;
typedef __attribute__((ext_vector_type(8))) short s16x8;   // 8 bf16 (MFMA A/B frag)
typedef __attribute__((ext_vector_type(4))) float f32x4;   // MFMA C/D frag
typedef __attribute__((ext_vector_type(4))) int   i32x4;

#define BATCH   64
#define SEQ     256
#define HID     1024
#define GATES   4096
#define NWG     256
#define THREADS 320          // waves 0-3 compute; wave 4 = aggregator (WG0/WG128) or exits
#define UNITS   8
#define NCOLS   32
#define ROWSTRIDE 2056       // 2048 K + 8 pad elems (LDS bank de-alias)
#define BH      (BATCH * HID)

#define H0_SLOTS 8           // slack-7 ring: L0 free-runs ahead
#define H1_SLOTS 2
// ---- ws layout ----
// prod flags: 1024 private lines (layer*512 + wgl*4 + wave), 128 B apart
// replicas:   32 lines (layer*16 + r)
#define PROD_OFF ((size_t)(H0_SLOTS + H1_SLOTS) * BH * 2)   // 1,310,720
#define REPS_OFF (PROD_OFF + 1024ull * 128)                 // +131,072
#define WS_NEED  (REPS_OFF + 32ull * 128)

#define OUT_HN  ((size_t)BATCH * SEQ * HID)
#define OUT_CN  (OUT_HN + 2ull * BATCH * HID)

__device__ __forceinline__ short f2bf(float f) {   // rne fp32->bf16
    unsigned int u = __builtin_bit_cast(unsigned int, f);
    u = (u + 0x7fffu + ((u >> 16) & 1u)) >> 16;
    return (short)u;
}

// ---- h GEMM over K=1024: coherent-point loads (sc0 sc1), single base +
// immediate offsets, counted-vmcnt pipeline, sched_barrier (rule #18). ----
#define GLD(i, OFF) asm volatile("global_load_dwordx4 %0, %1, off offset:" OFF " sc0 sc1" \
                                 : "=v"(h[i]) : "v"(xrow));
#define MM8(B0) \
    _Pragma("unroll") \
    for (int kk = (B0); kk < (B0) + 8; ++kk) { \
        s16x8 b0 = *(const s16x8*)(s0 + kk * 32); \
        s16x8 b1 = *(const s16x8*)(s1 + kk * 32); \
        s16x8 av = __builtin_bit_cast(s16x8, h[kk]); \
        a0 = __builtin_amdgcn_mfma_f32_16x16x32_bf16(av, b0, a0, 0, 0, 0); \
        a1 = __builtin_amdgcn_mfma_f32_16x16x32_bf16(av, b1, a1, 0, 0, 0); \
    }
__device__ __forceinline__ void gemm_bt(const bf16* xrow, const bf16* s0, const bf16* s1,
                                        f32x4& a0, f32x4& a1)
{
    i32x4 h[32];
    GLD(0,"0")    GLD(1,"64")   GLD(2,"128")  GLD(3,"192")
    GLD(4,"256")  GLD(5,"320")  GLD(6,"384")  GLD(7,"448")
    GLD(8,"512")  GLD(9,"576")  GLD(10,"640") GLD(11,"704")
    GLD(12,"768") GLD(13,"832") GLD(14,"896") GLD(15,"960")
    GLD(16,"1024") GLD(17,"1088") GLD(18,"1152") GLD(19,"1216")
    GLD(20,"1280") GLD(21,"1344") GLD(22,"1408") GLD(23,"1472")
    asm volatile("s_waitcnt vmcnt(16)"); __builtin_amdgcn_sched_barrier(0);
    MM8(0)
    GLD(24,"1536") GLD(25,"1600") GLD(26,"1664") GLD(27,"1728")
    GLD(28,"1792") GLD(29,"1856") GLD(30,"1920") GLD(31,"1984")
    asm volatile("s_waitcnt vmcnt(16)"); __builtin_amdgcn_sched_barrier(0);
    MM8(8)
    asm volatile("s_waitcnt vmcnt(8)");  __builtin_amdgcn_sched_barrier(0);
    MM8(16)
    asm volatile("s_waitcnt vmcnt(0)");  __builtin_amdgcn_sched_barrier(0);
    MM8(24)
}

// Embedding x-GEMM: plain cached fp32 loads.
__device__ __forceinline__ void gemm_f32c(const float* xrow, const bf16* s0, const bf16* s1,
                                          f32x4& a0, f32x4& a1)
{
#pragma unroll
    for (int c = 0; c < 4; ++c) {
        f32x4 xv[16];
#pragma unroll
        for (int i = 0; i < 8; ++i) {
            const float* p = xrow + (c * 8 + i) * 32;
            xv[2 * i]     = *(const f32x4*)p;
            xv[2 * i + 1] = *(const f32x4*)(p + 4);
        }
#pragma unroll
        for (int i = 0; i < 8; ++i) {
            const int kk = c * 8 + i;
            s16x8 af;
#pragma unroll
            for (int j = 0; j < 4; ++j) {
                af[j]     = f2bf(xv[2 * i][j]);
                af[4 + j] = f2bf(xv[2 * i + 1][j]);
            }
            s16x8 b0 = *(const s16x8*)(s0 + kk * 32);
            s16x8 b1 = *(const s16x8*)(s1 + kk * 32);
            a0 = __builtin_amdgcn_mfma_f32_16x16x32_bf16(af, b0, a0, 0, 0, 0);
            a1 = __builtin_amdgcn_mfma_f32_16x16x32_bf16(af, b1, a1, 0, 0, 0);
        }
    }
}

// Consumer poll: ONE uniform word (this wave's replica line) with seen-caching.
// 32 waves/replica-line at ~1 probe/us -> no same-line queueing.
__device__ __forceinline__ void rep_poll(unsigned int* rep, int tgt, int* seen) {
    if (tgt <= 0 || *seen >= tgt) return;
    int v;
    for (;;) {
        v = (int)__hip_atomic_load(rep, __ATOMIC_RELAXED, __HIP_MEMORY_SCOPE_AGENT);
        if (v >= tgt) break;
        __builtin_amdgcn_s_sleep(1);
    }
    *seen = v;
    asm volatile("" ::: "memory");
}

__global__ void ws_init(unsigned int* p, int n) {
    for (int i = blockIdx.x * blockDim.x + threadIdx.x; i < n; i += gridDim.x * blockDim.x)
        p[i] = 0u;
}

__global__ void __launch_bounds__(THREADS, 1)
lstm_enc(const int* __restrict__ src, const float* __restrict__ Wemb,
         const float* __restrict__ Wih, const float* __restrict__ Whh,
         const float* __restrict__ bih, const float* __restrict__ bhh,
         float* __restrict__ out, bf16* __restrict__ hbuf)
{
    __shared__ __align__(16) bf16 slab[NCOLS][ROWSTRIDE];   // 131,584 B
    __shared__ float bias[NCOLS];

    const int wg    = blockIdx.x;
    const int layer = wg >> 7;
    const int wgl   = wg & 127;
    const int j0    = wgl * UNITS;
    const int tid   = threadIdx.x;
    const int lane  = tid & 63;
    const int wave  = tid >> 6;                // 0-4

    // ---- weight slab (first 256 threads only; wave4 skips) ----
    if (tid < 256) {
        for (int r = 0; r < NCOLS; ++r) {
            int g = r >> 3, u = r & 7;
            size_t grow = (size_t)layer * GATES * HID + (size_t)(g * HID + j0 + u) * HID;
            int k = tid * 8;
            const float* s = (k < HID) ? (Wih + grow + k) : (Whh + grow + (k - HID));
            s16x8 v;
#pragma unroll
            for (int j = 0; j < 8; ++j) v[j] = f2bf(s[j]);
            *(s16x8*)&slab[r][k] = v;
        }
        if (tid < NCOLS) {
            int g = tid >> 3, u = tid & 7;
            int off = layer * GATES + g * HID + j0 + u;
            bias[tid] = bih[off] + bhh[off];
        }
    }
    __syncthreads();                           // only barrier (all 5 waves alive)

    bf16* h0 = hbuf;                           // [8][B][H] ring
    bf16* h1 = hbuf + H0_SLOTS * BH;           // [2][B][H] ring
    unsigned int* prod = (unsigned int*)((char*)hbuf + PROD_OFF);  // 1024 lines x 32 words
    unsigned int* reps = (unsigned int*)((char*)hbuf + REPS_OFF);  // 32 lines x 32 words

    // ================= aggregator wave (wave 4) =================
    if (wave == 4) {
        if (wgl == 0) {                        // wg 0 -> L0 agg; wg 128 -> L1 agg
            const int aggl = layer;
            unsigned int* pb = prod + (size_t)aggl * 512 * 32;
            unsigned int* rb = reps + (size_t)aggl * 16 * 32;
            int T = 1;
            while (T <= SEQ) {
                // batched probe of 512 private producer lines (8 x 64-lane loads)
                unsigned int v0,v1,v2,v3,v4,v5,v6,v7;
                const unsigned int* a0 = pb + ((size_t)0*64 + lane)*32;
                const unsigned int* a1 = pb + ((size_t)1*64 + lane)*32;
                const unsigned int* a2 = pb + ((size_t)2*64 + lane)*32;
                const unsigned int* a3 = pb + ((size_t)3*64 + lane)*32;
                const unsigned int* a4 = pb + ((size_t)4*64 + lane)*32;
                const unsigned int* a5 = pb + ((size_t)5*64 + lane)*32;
                const unsigned int* a6 = pb + ((size_t)6*64 + lane)*32;
                const unsigned int* a7 = pb + ((size_t)7*64 + lane)*32;
                asm volatile("global_load_dword %0, %1, off sc0 sc1" : "=v"(v0) : "v"(a0));
                asm volatile("global_load_dword %0, %1, off sc0 sc1" : "=v"(v1) : "v"(a1));
                asm volatile("global_load_dword %0, %1, off sc0 sc1" : "=v"(v2) : "v"(a2));
                asm volatile("global_load_dword %0, %1, off sc0 sc1" : "=v"(v3) : "v"(a3));
                asm volatile("global_load_dword %0, %1, off sc0 sc1" : "=v"(v4) : "v"(a4));
                asm volatile("global_load_dword %0, %1, off sc0 sc1" : "=v"(v5) : "v"(a5));
                asm volatile("global_load_dword %0, %1, off sc0 sc1" : "=v"(v6) : "v"(a6));
                asm volatile("global_load_dword %0, %1, off sc0 sc1" : "=v"(v7) : "v"(a7));
                asm volatile("s_waitcnt vmcnt(0)" ::: "memory");
                __builtin_amdgcn_sched_barrier(0);
                const unsigned int uT = (unsigned int)T;
                int ok = (v0 >= uT) && (v1 >= uT) && (v2 >= uT) && (v3 >= uT) &&
                         (v4 >= uT) && (v5 >= uT) && (v6 >= uT) && (v7 >= uT);
                if (__all(ok)) {
                    if (lane < 16)             // broadcast epoch to 16 replica lines
                        __hip_atomic_store(rb + lane * 32, uT,
                                           __ATOMIC_RELAXED, __HIP_MEMORY_SCOPE_AGENT);
                    ++T;                       // producers may be ahead: no sleep
                } else {
                    __builtin_amdgcn_s_sleep(1);
                }
            }
        }
        return;                                // wave 4 exits (no later barriers)
    }

    // ================= compute waves (0-3), R8 structure =================
    const int m     = lane & 15;
    const int q     = lane >> 4;
    const int kq    = q * 8;
    const int b_a   = wave * 16 + m;           // batch row this lane loads for A

    unsigned int* rep0 = reps + (size_t)(((wgl * 4 + wave) & 15)) * 32;            // L0 epoch
    unsigned int* rep1 = reps + (size_t)(16 + ((wgl * 4 + wave) & 15)) * 32;       // L1 epoch
    unsigned int* myprod = prod + (size_t)(layer * 512 + wgl * 4 + wave) * 32;     // private line

    const int u = m & 7;
    const float b_i = bias[u], b_f = bias[8 + u], b_g = bias[16 + u], b_o = bias[24 + u];
    float c_s[4] = {0.f, 0.f, 0.f, 0.f};
    int seenA = 0, seenB = 0;

    int sv = (layer == 0) ? src[b_a * SEQ] : 0;

    for (int t = 0; t < SEQ; ++t) {
        f32x4 acc0 = {0.f, 0.f, 0.f, 0.f};
        f32x4 acc1 = {0.f, 0.f, 0.f, 0.f};

        if (layer == 0) {
            // embedding x-GEMM: no cross-WG dep, overlaps the recurrence wait
            const float* xF = Wemb + (size_t)sv * HID + kq;
            if (t + 1 < SEQ) sv = src[b_a * SEQ + t + 1];
            gemm_f32c(xF, &slab[m][kq], &slab[16 + m][kq], acc0, acc1);
            rep_poll(rep0, t, &seenA);         // own layer done t-1
            if (t >= 1)
                gemm_bt(h0 + (size_t)((t - 1) & 7) * BH + b_a * HID + kq,
                        &slab[m][HID + kq], &slab[16 + m][HID + kq], acc0, acc1);
            rep_poll(rep1, t - 7, &seenB);     // ring protect (slack 7, mostly skipped)
        } else {
            rep_poll(rep0, t + 1, &seenA);     // L0 ahead -> mostly cached/skipped
            gemm_bt(h0 + (size_t)(t & 7) * BH + b_a * HID + kq,
                    &slab[m][kq], &slab[16 + m][kq], acc0, acc1);
            rep_poll(rep1, t, &seenB);         // own recurrence (the critical wait)
            if (t >= 1)
                gemm_bt(h1 + (size_t)((t - 1) & 1) * BH + b_a * HID + kq,
                        &slab[m][HID + kq], &slab[16 + m][HID + kq], acc0, acc1);
        }

        // in-wave epilogue: gate pairs sit in lane pair (u, u+8); bitwise-same math
        float hval[4];
#pragma unroll
        for (int r = 0; r < 4; ++r) {
            float p0 = __shfl_xor(acc0[r], 8, 64);
            float p1 = __shfl_xor(acc1[r], 8, 64);
            const bool lo = (m < 8);
            float gi = (lo ? acc0[r] : p0) + b_i;
            float gf = (lo ? p0 : acc0[r]) + b_f;
            float gg = (lo ? acc1[r] : p1) + b_g;
            float go = (lo ? p1 : acc1[r]) + b_o;
            float si = 1.f / (1.f + __expf(-gi));
            float sf = 1.f / (1.f + __expf(-gf));
            float so = 1.f / (1.f + __expf(-go));
            c_s[r] = sf * c_s[r] + si * tanhf(gg);
            hval[r] = so * tanhf(c_s[r]);
        }

        // h ring store (lanes m<8 own the unique copy), write-through to MALL
        bf16* hw = (layer == 0) ? h0 + (size_t)(t & 7) * BH
                                : h1 + (size_t)(t & 1) * BH;
        if (m < 8) {
#pragma unroll
            for (int r = 0; r < 4; ++r) {
                int R = wave * 16 + q * 4 + r;
                __hip_atomic_store((unsigned short*)(hw + (size_t)R * HID + j0 + u),
                                   (unsigned short)f2bf(hval[r]),
                                   __ATOMIC_RELAXED, __HIP_MEMORY_SCOPE_AGENT);
            }
        }
        // per-wave drain + private-line flag post (no store contention)
        asm volatile("s_waitcnt vmcnt(0)"); __builtin_amdgcn_sched_barrier(0);
        asm volatile("" ::: "memory");
        if (lane == 0)
            __hip_atomic_store(myprod, (unsigned int)(t + 1),
                               __ATOMIC_RELAXED, __HIP_MEMORY_SCOPE_AGENT);

        // post-flag outputs: off the recurrence critical path
        if (layer == 1 && m < 8) {
#pragma unroll
            for (int r = 0; r < 4; ++r) {
                int R = wave * 16 + q * 4 + r;
                out[((size_t)R * SEQ + t) * HID + j0 + u] = hval[r];
            }
        }
        if (t == SEQ - 1 && m < 8) {
#pragma unroll
            for (int r = 0; r < 4; ++r) {
                int R = wave * 16 + q * 4 + r;
                size_t o = ((size_t)layer * BATCH + R) * HID + j0 + u;
                out[OUT_HN + o] = hval[r];
                out[OUT_CN + o] = c_s[r];
            }
        }
    }
}

extern "C" void kernel_launch(void* const* d_in, const int* in_sizes, int n_in,
                              void* d_out, int out_size, void* d_ws, size_t ws_size,
                              hipStream_t stream) {
    const int*   src  = (const int*)d_in[0];
    const float* emb  = (const float*)d_in[1];
    const float* W_ih = (const float*)d_in[2];
    const float* W_hh = (const float*)d_in[3];
    const float* b_ih = (const float*)d_in[4];
    const float* b_hh = (const float*)d_in[5];
    float* out  = (float*)d_out;
    bf16*  hbuf = (bf16*)d_ws;

    // zero prod lines + replica lines (ws re-poisoned 0xAA each replay;
    // rings need no init: every slot is written before it is ever read)
    unsigned int* wsp = (unsigned int*)((char*)d_ws + PROD_OFF);
    ws_init<<<36, 256, 0, stream>>>(wsp, (1024 + 32) * 32);

    void* args[] = {&src, &emb, &W_ih, &W_hh, &b_ih, &b_hh, &out, &hbuf};
    hipLaunchCooperativeKernel((void*)lstm_enc, dim3(NWG), dim3(THREADS),
                               args, 0, stream);
}